// Round 10
// baseline (134.076 us; speedup 1.0000x reference)
//
#include <hip/hip_runtime.h>
#include <hip/hip_bf16.h>
#include <stdint.h>

#define NN 4096
#define SLOPE 0.2f
#define LOG2E 1.44269504088896340736f

typedef float f32x4 __attribute__((ext_vector_type(4)));
typedef short s16x8 __attribute__((ext_vector_type(8)));
typedef unsigned u32x4 __attribute__((ext_vector_type(4)));

static __device__ __forceinline__ unsigned f32_to_bf16_rne(float f) {
    unsigned u = __builtin_bit_cast(unsigned, f);
    return (u + 0x7FFFu + ((u >> 16) & 1u)) >> 16;
}

// ---------------------------------------------------------------------------
// K1: Wx GEMM only (256 blocks; pack path removed — K2 stages adjacency
// itself).  VERBATIM the Wx path of R4/R9's k01 (passing, absmax 0.03125).
// ---------------------------------------------------------------------------
__global__ __launch_bounds__(256) void k1_wx(const float* __restrict__ x,
                                             const float* __restrict__ W,
                                             const float* __restrict__ a,
                                             unsigned* __restrict__ wxb8,
                                             float* __restrict__ ai_s,
                                             float* __restrict__ ajT_s) {
    __shared__ unsigned short WL[128 * 136];
    __shared__ unsigned short XL[16 * 136];
    __shared__ float WxF[16 * 132];

    const int t = threadIdx.x;
    const int i0 = blockIdx.x * 16;

    for (int p4 = t; p4 < 4096; p4 += 256) {
        f32x4 w4 = *(const f32x4*)(W + 4 * p4);
        unsigned lo = f32_to_bf16_rne(w4.x) | (f32_to_bf16_rne(w4.y) << 16);
        unsigned hi = f32_to_bf16_rne(w4.z) | (f32_to_bf16_rne(w4.w) << 16);
        int c = (4 * p4) >> 7, k = (4 * p4) & 127;
        *(unsigned long long*)&WL[c * 136 + k] =
            (unsigned long long)lo | ((unsigned long long)hi << 32);
    }
    for (int p4 = t; p4 < 512; p4 += 256) {
        f32x4 x4 = *(const f32x4*)(x + (long)i0 * 128 + 4 * p4);
        unsigned lo = f32_to_bf16_rne(x4.x) | (f32_to_bf16_rne(x4.y) << 16);
        unsigned hi = f32_to_bf16_rne(x4.z) | (f32_to_bf16_rne(x4.w) << 16);
        int r = (4 * p4) >> 7, k = (4 * p4) & 127;
        *(unsigned long long*)&XL[r * 136 + k] =
            (unsigned long long)lo | ((unsigned long long)hi << 32);
    }
    __syncthreads();

    const int w = t >> 6, l = t & 63, m = l & 15, q = l >> 4;
    f32x4 acc0 = {0.f, 0.f, 0.f, 0.f}, acc1 = {0.f, 0.f, 0.f, 0.f};
    #pragma unroll
    for (int ks = 0; ks < 4; ++ks) {
        s16x8 af = *(const s16x8*)&XL[m * 136 + ks * 32 + q * 8];
        s16x8 b0 = *(const s16x8*)&WL[(w * 32 + m) * 136 + ks * 32 + q * 8];
        s16x8 b1 = *(const s16x8*)&WL[(w * 32 + 16 + m) * 136 + ks * 32 + q * 8];
        acc0 = __builtin_amdgcn_mfma_f32_16x16x32_bf16(af, b0, acc0, 0, 0, 0);
        acc1 = __builtin_amdgcn_mfma_f32_16x16x32_bf16(af, b1, acc1, 0, 0, 0);
    }
    const int jblk = i0 >> 5;
    const int qp = ((i0 & 16) + q * 4) >> 3;
    const int ehalf = q & 1;
    #pragma unroll
    for (int j2 = 0; j2 < 2; ++j2) {
        f32x4 acc = j2 ? acc1 : acc0;
        unsigned u = (unsigned)__builtin_amdgcn_cvt_pk_fp8_f32(acc[0], acc[1], 0, false);
        u = (unsigned)__builtin_amdgcn_cvt_pk_fp8_f32(acc[2], acc[3], (int)u, true);
        wxb8[(((jblk * 4 + w) * 64 + qp * 16 + m) << 2) + j2 * 2 + ehalf] = u;
        #pragma unroll
        for (int reg = 0; reg < 4; ++reg)
            WxF[(q * 4 + reg) * 132 + (2 * w + j2) * 16 + m] = acc[reg];
    }
    __syncthreads();
    if (t < 64) {
        int r = t >> 2, h = t & 3;
        float s_i = 0.f, s_j = 0.f;
        const float* ar = a + h * 64;
        #pragma unroll
        for (int d = 0; d < 32; ++d) {
            float wv = WxF[r * 132 + h * 32 + d];
            s_i += wv * ar[d];
            s_j += wv * ar[32 + d];
        }
        ai_s[(i0 + r) * 4 + h] = s_i * LOG2E;
        ajT_s[h * NN + i0 + r] = s_j * LOG2E;
    }
}

// ---------------------------------------------------------------------------
// K2: flash-style masked softmax + PV + residual + LayerNorm.
// Loop/epilogue VERBATIM from R9 (132 us, absmax 0.03125).  ONE change:
// adjacency bitmask is now packed in-kernel from the RAW input (R8's proven
// staging block, same maskL layout) instead of a separate pack kernel.
// ---------------------------------------------------------------------------
__global__ __launch_bounds__(1024, 4) void k2_attn(
        const float* __restrict__ x,
        const unsigned* __restrict__ adj_raw,
        const unsigned* __restrict__ wxb8,
        const float* __restrict__ ai_s,
        const float* __restrict__ ajT_s,
        const float* __restrict__ gamma,
        const float* __restrict__ beta,
        float* __restrict__ out) {
    __shared__ float ajL[4][4096];       // 64 KB
    __shared__ unsigned maskL[16][132];  // 8.4 KB (stride 132 -> 2-way, free)
    __shared__ float C_lds[4][16][32];   // 8 KB
    __shared__ float l_lds[4][16];

    const int t = threadIdx.x;
    const int i0 = blockIdx.x * 16;
    const int w = t >> 6, l = t & 63;
    const int h = w & 3, p = w >> 2;     // p in 0..3
    const int m = l & 15, q = l >> 4;
    const int rt = t >> 6, ct = t & 63;  // staging row / col-thread

    // dtype detect: int32 upload -> first 32 dwords all <= 1 (proven R8)
    unsigned dv = adj_raw[l & 31];
    const bool is_i32 = __all(dv <= 1u) != 0;

    {   // stage ajT (all 4 heads), coalesced f32x4  [R9 verbatim]
        const f32x4* src = (const f32x4*)ajT_s;
        f32x4* dst = (f32x4*)&ajL[0][0];
        #pragma unroll
        for (int g = 0; g < 4; ++g) dst[t + 1024 * g] = src[t + 1024 * g];
    }
    {   // stage adjacency rows i0..i0+15 -> LDS bitmask  [R8 verbatim]
        unsigned short* mh = (unsigned short*)&maskL[0][0];
        if (is_i32) {
            #pragma unroll
            for (int c = 0; c < 4; ++c) {
                const u32x4* ps = (const u32x4*)(adj_raw + (long)(i0 + rt) * NN +
                                                 c * 1024 + ct * 16);
                u32x4 r0 = ps[0], r1 = ps[1], r2 = ps[2], r3 = ps[3];
                unsigned b =
                    (r0.x & 1u) | ((r0.y & 1u) << 1) | ((r0.z & 1u) << 2) | ((r0.w & 1u) << 3) |
                    ((r1.x & 1u) << 4) | ((r1.y & 1u) << 5) | ((r1.z & 1u) << 6) | ((r1.w & 1u) << 7) |
                    ((r2.x & 1u) << 8) | ((r2.y & 1u) << 9) | ((r2.z & 1u) << 10) | ((r2.w & 1u) << 11) |
                    ((r3.x & 1u) << 12) | ((r3.y & 1u) << 13) | ((r3.z & 1u) << 14) | ((r3.w & 1u) << 15);
                mh[(rt * 132 + c * 32 + (ct >> 1)) * 2 + (ct & 1)] = (unsigned short)b;
            }
        } else {
            #pragma unroll
            for (int c = 0; c < 4; ++c) {
                const u32x4* ps = (const u32x4*)((const unsigned char*)adj_raw +
                                                 (long)(i0 + rt) * NN + c * 1024 + ct * 16);
                u32x4 r0 = ps[0];
                unsigned n0 = (((r0.x & 0x01010101u) * 0x08040201u) >> 24) & 0xFu;
                unsigned n1 = (((r0.y & 0x01010101u) * 0x08040201u) >> 24) & 0xFu;
                unsigned n2 = (((r0.z & 0x01010101u) * 0x08040201u) >> 24) & 0xFu;
                unsigned n3 = (((r0.w & 0x01010101u) * 0x08040201u) >> 24) & 0xFu;
                unsigned b = n0 | (n1 << 4) | (n2 << 8) | (n3 << 12);
                mh[(rt * 132 + c * 32 + (ct >> 1)) * 2 + (ct & 1)] = (unsigned short)b;
            }
        }
    }
    const float ai = ai_s[(i0 + m) * 4 + h];
    __syncthreads();

    const unsigned* bp8 = wxb8 + ((h * 64 + l) << 2);  // 16 B per lane
    const float* ajh = &ajL[h][0] + q * 8;
    const long ONESB = 0x3838383838383838L;            // e4m3 1.0 x8

    f32x4 acc0 = {0.f, 0.f, 0.f, 0.f}, acc1 = {0.f, 0.f, 0.f, 0.f};
    f32x4 accl = {0.f, 0.f, 0.f, 0.f};

    // 2-deep B prefetch: bv0 = iter ks, bv1 = iter ks+4  [R9 verbatim]
    u32x4 bv0 = *(const u32x4*)(bp8 + (p << 10));
    u32x4 bv1 = *(const u32x4*)(bp8 + (((p + 4 < 128) ? p + 4 : p) << 10));
    for (int ks = p; ks < 128; ks += 4) {   // 32 j per step
        const int ksn2 = (ks + 8 < 128) ? (ks + 8) : ks;
        u32x4 bv2 = *(const u32x4*)(bp8 + (ksn2 << 10));  // prefetch ks+8

        unsigned mq = (maskL[m][ks] >> (q * 8)) & 0xffu;
        f32x4 aj0 = *(const f32x4*)(ajh + ks * 32);
        f32x4 aj1 = *(const f32x4*)(ajh + ks * 32 + 4);

        float ev[8];
        #pragma unroll
        for (int e = 0; e < 8; ++e) {
            float s = ai + (e < 4 ? aj0[e] : aj1[e - 4]);   // already * log2e
            s = fmaxf(s, SLOPE * s);                        // lrelu (scale-inv)
            float ex = __builtin_amdgcn_exp2f(s);
            ev[e] = ((mq >> e) & 1u) ? ex : 0.0f;
        }
        unsigned d0 = (unsigned)__builtin_amdgcn_cvt_pk_bf8_f32(ev[0], ev[1], 0, false);
        d0 = (unsigned)__builtin_amdgcn_cvt_pk_bf8_f32(ev[2], ev[3], (int)d0, true);
        unsigned d1 = (unsigned)__builtin_amdgcn_cvt_pk_bf8_f32(ev[4], ev[5], 0, false);
        d1 = (unsigned)__builtin_amdgcn_cvt_pk_bf8_f32(ev[6], ev[7], (int)d1, true);
        long av = (long)(((unsigned long long)d1 << 32) | d0);
        long b0 = (long)(((unsigned long long)bv0.y << 32) | bv0.x);
        long b1 = (long)(((unsigned long long)bv0.w << 32) | bv0.z);

        acc0 = __builtin_amdgcn_mfma_f32_16x16x32_bf8_fp8(av, b0, acc0, 0, 0, 0);
        acc1 = __builtin_amdgcn_mfma_f32_16x16x32_bf8_fp8(av, b1, acc1, 0, 0, 0);
        accl = __builtin_amdgcn_mfma_f32_16x16x32_bf8_fp8(av, ONESB, accl, 0, 0, 0);
        bv0 = bv1; bv1 = bv2;
    }

    // combine the 4 parity partials  [R9 verbatim]
    if (p == 0) {
        #pragma unroll
        for (int reg = 0; reg < 4; ++reg) {
            C_lds[h][q * 4 + reg][m] = acc0[reg];
            C_lds[h][q * 4 + reg][16 + m] = acc1[reg];
            if (m == 0) l_lds[h][q * 4 + reg] = accl[reg];
        }
    }
    __syncthreads();
    if (p == 1) {
        #pragma unroll
        for (int reg = 0; reg < 4; ++reg) {
            C_lds[h][q * 4 + reg][m] += acc0[reg];
            C_lds[h][q * 4 + reg][16 + m] += acc1[reg];
            if (m == 0) l_lds[h][q * 4 + reg] += accl[reg];
        }
    }
    __syncthreads();
    if (p == 2) {
        #pragma unroll
        for (int reg = 0; reg < 4; ++reg) {
            C_lds[h][q * 4 + reg][m] += acc0[reg];
            C_lds[h][q * 4 + reg][16 + m] += acc1[reg];
            if (m == 0) l_lds[h][q * 4 + reg] += accl[reg];
        }
    }
    __syncthreads();
    if (p == 3) {
        #pragma unroll
        for (int reg = 0; reg < 4; ++reg) {
            C_lds[h][q * 4 + reg][m] += acc0[reg];
            C_lds[h][q * 4 + reg][16 + m] += acc1[reg];
            if (m == 0) l_lds[h][q * 4 + reg] += accl[reg];
        }
    }
    __syncthreads();

    // epilogue: normalize, residual, LayerNorm.  [R9 verbatim]
    if (t < 512) {
        const int r = t >> 5, c32 = t & 31;
        const int f0 = c32 * 4;
        const int hh = f0 >> 5, cl = f0 & 31;
        const float linv = 1.0f / l_lds[hh][r];
        f32x4 xv = *(const f32x4*)(x + (long)(i0 + r) * 128 + f0);
        float y[4], s1 = 0.f, s2 = 0.f;
        #pragma unroll
        for (int kk = 0; kk < 4; ++kk) {
            float yy = C_lds[hh][r][cl + kk] * linv + xv[kk];
            y[kk] = yy; s1 += yy; s2 += yy * yy;
        }
        #pragma unroll
        for (int s = 1; s <= 16; s <<= 1) {
            s1 += __shfl_xor(s1, s, 64);
            s2 += __shfl_xor(s2, s, 64);
        }
        const float mean = s1 * (1.0f / 128.0f);
        const float var = s2 * (1.0f / 128.0f) - mean * mean;
        const float rstd = rsqrtf(var + 1e-5f);
        f32x4 gv = *(const f32x4*)(gamma + f0);
        f32x4 bv2 = *(const f32x4*)(beta + f0);
        f32x4 ov;
        #pragma unroll
        for (int kk = 0; kk < 4; ++kk)
            ov[kk] = gv[kk] * ((y[kk] - mean) * rstd) + bv2[kk];
        *(f32x4*)(out + (long)(i0 + r) * 128 + f0) = ov;
    }
}

extern "C" void kernel_launch(void* const* d_in, const int* in_sizes, int n_in,
                              void* d_out, int out_size, void* d_ws, size_t ws_size,
                              hipStream_t stream) {
    const float* x = (const float*)d_in[0];
    const unsigned* adj_raw = (const unsigned*)d_in[1];
    const float* W = (const float*)d_in[2];
    const float* a = (const float*)d_in[3];
    const float* gamma = (const float*)d_in[4];
    const float* beta = (const float*)d_in[5];

    unsigned* wxb8 = (unsigned*)d_ws;                                   // 512 KB
    float* ai_s = (float*)((char*)d_ws + (512 << 10));                  // 64 KB
    float* ajT_s = (float*)((char*)d_ws + (576 << 10));                 // 64 KB

    k1_wx<<<256, 256, 0, stream>>>(x, W, a, wxb8, ai_s, ajT_s);
    k2_attn<<<256, 1024, 0, stream>>>(x, adj_raw, wxb8, ai_s, ajT_s, gamma, beta,
                                      (float*)d_out);
}

// Round 11
// 129.292 us; speedup vs baseline: 1.0370x; 1.0370x over previous
//
#include <hip/hip_runtime.h>
#include <stdint.h>

#define NN 4096
#define LOG2E 1.44269504088896340736f

typedef float f32x4 __attribute__((ext_vector_type(4)));
typedef short s16x8 __attribute__((ext_vector_type(8)));
typedef unsigned u32x4 __attribute__((ext_vector_type(4)));
typedef _Float16 f16x2 __attribute__((ext_vector_type(2)));

static __device__ __forceinline__ unsigned f32_to_bf16_rne(float f) {
    unsigned u = __builtin_bit_cast(unsigned, f);
    return (u + 0x7FFFu + ((u >> 16) & 1u)) >> 16;
}
static __device__ __forceinline__ unsigned f16bits(float f) {
    _Float16 h = (_Float16)f;
    return (unsigned)__builtin_bit_cast(unsigned short, h);
}

// ---------------------------------------------------------------------------
// K01: fused adjacency-pack (blocks 0..2047, R9-verbatim) + Wx GEMM
// (blocks 2048..2303).  GEMM path emits wxb16 (f16 B-frags, R5/R8-proven
// layout), ai_s (f32 alpha_i*log2e), ejfj (combined dword E|F<<16 per (h,j),
// R8-proven values/layout).
// ---------------------------------------------------------------------------
__global__ __launch_bounds__(256) void k01(const unsigned* __restrict__ adj_raw,
                                           const float* __restrict__ x,
                                           const float* __restrict__ W,
                                           const float* __restrict__ a,
                                           unsigned* __restrict__ bits,
                                           unsigned* __restrict__ wxb16,
                                           float* __restrict__ ai_s,
                                           unsigned* __restrict__ ejfj) {
    const int t = threadIdx.x;
    if (blockIdx.x < 2048) {
        __shared__ int s_i32;
        if (t == 0) {
            int all_small = 1;
            for (int i = 0; i < 32; ++i) all_small &= (adj_raw[i] <= 1u);
            s_i32 = all_small;
        }
        __syncthreads();
        const long o = (long)blockIdx.x * 256 + t;
        unsigned mm = 0;
        if (s_i32) {
            const u32x4* p = (const u32x4*)adj_raw + o * 8;  // 32 ints
            #pragma unroll
            for (int g = 0; g < 8; ++g) {
                u32x4 v = p[g];
                mm |= (v.x & 1u) << (g * 4) | (v.y & 1u) << (g * 4 + 1) |
                      (v.z & 1u) << (g * 4 + 2) | (v.w & 1u) << (g * 4 + 3);
            }
        } else {
            const u32x4* p = (const u32x4*)adj_raw + o * 2;  // 32 bytes
            #pragma unroll
            for (int g = 0; g < 2; ++g) {
                u32x4 v = p[g];
                unsigned d[4] = {v.x, v.y, v.z, v.w};
                #pragma unroll
                for (int qq = 0; qq < 4; ++qq)
                    #pragma unroll
                    for (int b = 0; b < 4; ++b)
                        mm |= ((d[qq] >> (8 * b)) & 1u) << (g * 16 + qq * 4 + b);
            }
        }
        bits[o] = mm;
        return;
    }

    // ---- Wx GEMM path ----
    __shared__ unsigned short WL[128 * 136];
    __shared__ unsigned short XL[16 * 136];
    __shared__ float WxF[16 * 132];

    const int bid = blockIdx.x - 2048;
    const int i0 = bid * 16;

    for (int p4 = t; p4 < 4096; p4 += 256) {
        f32x4 w4 = *(const f32x4*)(W + 4 * p4);
        unsigned lo = f32_to_bf16_rne(w4.x) | (f32_to_bf16_rne(w4.y) << 16);
        unsigned hi = f32_to_bf16_rne(w4.z) | (f32_to_bf16_rne(w4.w) << 16);
        int c = (4 * p4) >> 7, k = (4 * p4) & 127;
        *(unsigned long long*)&WL[c * 136 + k] =
            (unsigned long long)lo | ((unsigned long long)hi << 32);
    }
    for (int p4 = t; p4 < 512; p4 += 256) {
        f32x4 x4 = *(const f32x4*)(x + (long)i0 * 128 + 4 * p4);
        unsigned lo = f32_to_bf16_rne(x4.x) | (f32_to_bf16_rne(x4.y) << 16);
        unsigned hi = f32_to_bf16_rne(x4.z) | (f32_to_bf16_rne(x4.w) << 16);
        int r = (4 * p4) >> 7, k = (4 * p4) & 127;
        *(unsigned long long*)&XL[r * 136 + k] =
            (unsigned long long)lo | ((unsigned long long)hi << 32);
    }
    __syncthreads();

    const int w = t >> 6, l = t & 63, m = l & 15, q = l >> 4;
    f32x4 acc0 = {0.f, 0.f, 0.f, 0.f}, acc1 = {0.f, 0.f, 0.f, 0.f};
    #pragma unroll
    for (int ks = 0; ks < 4; ++ks) {
        s16x8 af = *(const s16x8*)&XL[m * 136 + ks * 32 + q * 8];
        s16x8 b0 = *(const s16x8*)&WL[(w * 32 + m) * 136 + ks * 32 + q * 8];
        s16x8 b1 = *(const s16x8*)&WL[(w * 32 + 16 + m) * 136 + ks * 32 + q * 8];
        acc0 = __builtin_amdgcn_mfma_f32_16x16x32_bf16(af, b0, acc0, 0, 0, 0);
        acc1 = __builtin_amdgcn_mfma_f32_16x16x32_bf16(af, b1, acc1, 0, 0, 0);
    }
    // f16 B-frag store (R5/R8-proven indices)
    const int jblk = i0 >> 5;
    const int qslot = ((i0 & 16) + q * 4) >> 3;
    const int dhalf = q & 1;
    #pragma unroll
    for (int j2 = 0; j2 < 2; ++j2) {
        const int fblk = 2 * w + j2;
        f32x4 acc = j2 ? acc1 : acc0;
        unsigned d01 = f16bits(acc[0]) | (f16bits(acc[1]) << 16);
        unsigned d23 = f16bits(acc[2]) | (f16bits(acc[3]) << 16);
        unsigned* wp = wxb16 + (((jblk * 8 + fblk) * 64 + qslot * 16 + m) << 2) + dhalf * 2;
        wp[0] = d01;
        wp[1] = d23;
        #pragma unroll
        for (int reg = 0; reg < 4; ++reg)
            WxF[(q * 4 + reg) * 132 + fblk * 16 + m] = acc[reg];
    }
    __syncthreads();
    if (t < 64) {
        int r = t >> 2, h = t & 3;
        float s_i = 0.f, s_j = 0.f;
        const float* ar = a + h * 64;
        #pragma unroll
        for (int d = 0; d < 32; ++d) {
            float wv = WxF[r * 132 + h * 32 + d];
            s_i += wv * ar[d];
            s_j += wv * ar[32 + d];
        }
        ai_s[(i0 + r) * 4 + h] = s_i * LOG2E;
        float sjl = s_j * LOG2E;
        ejfj[h * NN + i0 + r] = f16bits(exp2f(sjl)) | (f16bits(exp2f(0.2f * sjl)) << 16);
    }
}

// ---------------------------------------------------------------------------
// K2: masked softmax + PV + residual + LayerNorm.  Frame VERBATIM R9 (132 us):
// ef staging like R9's ajT staging, maskL from adjbits, 2-deep B prefetch,
// parity combine, epilogue.  Score block: exp-free pk-f16
// p = max(Ei*Ej, Fi*Fj) — 2 perm + 2 pk_mul + pk_max + mask per 2 elems.
// ---------------------------------------------------------------------------
__global__ __launch_bounds__(1024, 4) void k2_attn(
        const float* __restrict__ x,
        const unsigned* __restrict__ adjbits,
        const unsigned* __restrict__ wxb16,
        const float* __restrict__ ai_s,
        const unsigned* __restrict__ ejfj,
        const float* __restrict__ gamma,
        const float* __restrict__ beta,
        float* __restrict__ out) {
    __shared__ unsigned efL[4][4096];    // 64 KB: (E|F<<16) per (h,j)
    __shared__ unsigned maskL[16][132];  // 8.4 KB (stride 132 -> 2-way, free)
    __shared__ float C_lds[4][16][32];   // 8 KB
    __shared__ float l_lds[4][16];

    const int t = threadIdx.x;
    const int i0 = blockIdx.x * 16;
    const int w = t >> 6, l = t & 63;
    const int h = w & 3, p = w >> 2;     // p in 0..3
    const int m = l & 15, q = l >> 4;

    {   // stage ejfj (all 4 heads), coalesced u32x4  [R9 ajL staging pattern]
        const u32x4* src = (const u32x4*)ejfj;
        u32x4* dst = (u32x4*)&efL[0][0];
        #pragma unroll
        for (int g = 0; g < 4; ++g) dst[t + 1024 * g] = src[t + 1024 * g];
    }
    {   // stage adjacency bitmask rows i0..i0+15  [R9 verbatim]
        #pragma unroll
        for (int g = 0; g < 2; ++g) {
            int idx = t + 1024 * g;
            int r = idx >> 7, c = idx & 127;
            maskL[r][c] = adjbits[(long)(i0 + r) * 128 + c];
        }
    }
    const float aif = ai_s[(i0 + m) * 4 + h];
    const _Float16 eiH = (_Float16)exp2f(aif);
    const _Float16 fiH = (_Float16)exp2f(0.2f * aif);
    const f16x2 Ei2 = {eiH, eiH};
    const f16x2 Fi2 = {fiH, fiH};
    __syncthreads();

    const unsigned* bp16 = wxb16 + ((2 * h) * 64 + l) * 4;  // + ks*2048 dwords
    const unsigned* efh = &efL[h][0] + q * 8;
    const s16x8 ONESH = {0x3C00, 0x3C00, 0x3C00, 0x3C00,
                         0x3C00, 0x3C00, 0x3C00, 0x3C00};

    f32x4 acc0 = {0.f, 0.f, 0.f, 0.f}, acc1 = {0.f, 0.f, 0.f, 0.f};
    f32x4 accl = {0.f, 0.f, 0.f, 0.f};

    // 2-deep B prefetch (both fblk halves)  [R9 pattern, doubled for f16]
    const int ks1 = (p + 4 < 128) ? p + 4 : p;
    u32x4 pa0 = *(const u32x4*)(bp16 + p * 2048);
    u32x4 pb0 = *(const u32x4*)(bp16 + p * 2048 + 256);
    u32x4 pa1 = *(const u32x4*)(bp16 + ks1 * 2048);
    u32x4 pb1 = *(const u32x4*)(bp16 + ks1 * 2048 + 256);

    for (int ks = p; ks < 128; ks += 4) {   // 32 j per step
        const int ksn2 = (ks + 8 < 128) ? (ks + 8) : ks;
        u32x4 pa2 = *(const u32x4*)(bp16 + ksn2 * 2048);
        u32x4 pb2 = *(const u32x4*)(bp16 + ksn2 * 2048 + 256);

        unsigned mq = (maskL[m][ks] >> (q * 8)) & 0xffu;
        u32x4 ef0 = *(const u32x4*)(efh + ks * 32);      // j0..j0+3
        u32x4 ef1 = *(const u32x4*)(efh + ks * 32 + 4);  // j0+4..j0+7
        unsigned efu[8] = {ef0.x, ef0.y, ef0.z, ef0.w, ef1.x, ef1.y, ef1.z, ef1.w};

        union { s16x8 v; unsigned u[4]; } af;
        #pragma unroll
        for (int pr = 0; pr < 4; ++pr) {
            unsigned d0 = efu[2 * pr], d1 = efu[2 * pr + 1];
            unsigned Ep = __builtin_amdgcn_perm(d1, d0, 0x05040100);  // (E_j0, E_j1)
            unsigned Fp = __builtin_amdgcn_perm(d1, d0, 0x07060302);  // (F_j0, F_j1)
            f16x2 mE = Ei2 * __builtin_bit_cast(f16x2, Ep);
            f16x2 mF = Fi2 * __builtin_bit_cast(f16x2, Fp);
            f16x2 mx = __builtin_elementwise_max(mE, mF);
            unsigned lo = (unsigned)(-(int)((mq >> (2 * pr)) & 1u));
            unsigned hi = (unsigned)(-(int)((mq >> (2 * pr + 1)) & 1u));
            unsigned msk = (lo & 0xFFFFu) | (hi & 0xFFFF0000u);
            af.u[pr] = __builtin_bit_cast(unsigned, mx) & msk;
        }
        union { u32x4 u; s16x8 s; } b0c, b1c;
        b0c.u = pa0; b1c.u = pb0;
        acc0 = __builtin_amdgcn_mfma_f32_16x16x32_f16(af.v, b0c.s, acc0, 0, 0, 0);
        acc1 = __builtin_amdgcn_mfma_f32_16x16x32_f16(af.v, b1c.s, acc1, 0, 0, 0);
        accl = __builtin_amdgcn_mfma_f32_16x16x32_f16(af.v, ONESH, accl, 0, 0, 0);
        pa0 = pa1; pb0 = pb1; pa1 = pa2; pb1 = pb2;
    }

    // combine the 4 parity partials  [R9 verbatim]
    if (p == 0) {
        #pragma unroll
        for (int reg = 0; reg < 4; ++reg) {
            C_lds[h][q * 4 + reg][m] = acc0[reg];
            C_lds[h][q * 4 + reg][16 + m] = acc1[reg];
            if (m == 0) l_lds[h][q * 4 + reg] = accl[reg];
        }
    }
    __syncthreads();
    if (p == 1) {
        #pragma unroll
        for (int reg = 0; reg < 4; ++reg) {
            C_lds[h][q * 4 + reg][m] += acc0[reg];
            C_lds[h][q * 4 + reg][16 + m] += acc1[reg];
            if (m == 0) l_lds[h][q * 4 + reg] += accl[reg];
        }
    }
    __syncthreads();
    if (p == 2) {
        #pragma unroll
        for (int reg = 0; reg < 4; ++reg) {
            C_lds[h][q * 4 + reg][m] += acc0[reg];
            C_lds[h][q * 4 + reg][16 + m] += acc1[reg];
            if (m == 0) l_lds[h][q * 4 + reg] += accl[reg];
        }
    }
    __syncthreads();
    if (p == 3) {
        #pragma unroll
        for (int reg = 0; reg < 4; ++reg) {
            C_lds[h][q * 4 + reg][m] += acc0[reg];
            C_lds[h][q * 4 + reg][16 + m] += acc1[reg];
            if (m == 0) l_lds[h][q * 4 + reg] += accl[reg];
        }
    }
    __syncthreads();

    // epilogue: normalize, residual, LayerNorm.  [R9 verbatim]
    if (t < 512) {
        const int r = t >> 5, c32 = t & 31;
        const int f0 = c32 * 4;
        const int hh = f0 >> 5, cl = f0 & 31;
        const float linv = 1.0f / l_lds[hh][r];
        f32x4 xv = *(const f32x4*)(x + (long)(i0 + r) * 128 + f0);
        float y[4], s1 = 0.f, s2 = 0.f;
        #pragma unroll
        for (int kk = 0; kk < 4; ++kk) {
            float yy = C_lds[hh][r][cl + kk] * linv + xv[kk];
            y[kk] = yy; s1 += yy; s2 += yy * yy;
        }
        #pragma unroll
        for (int s = 1; s <= 16; s <<= 1) {
            s1 += __shfl_xor(s1, s, 64);
            s2 += __shfl_xor(s2, s, 64);
        }
        const float mean = s1 * (1.0f / 128.0f);
        const float var = s2 * (1.0f / 128.0f) - mean * mean;
        const float rstd = rsqrtf(var + 1e-5f);
        f32x4 gv = *(const f32x4*)(gamma + f0);
        f32x4 bv = *(const f32x4*)(beta + f0);
        f32x4 ov;
        #pragma unroll
        for (int kk = 0; kk < 4; ++kk)
            ov[kk] = gv[kk] * ((y[kk] - mean) * rstd) + bv[kk];
        *(f32x4*)(out + (long)(i0 + r) * 128 + f0) = ov;
    }
}

extern "C" void kernel_launch(void* const* d_in, const int* in_sizes, int n_in,
                              void* d_out, int out_size, void* d_ws, size_t ws_size,
                              hipStream_t stream) {
    const float* x = (const float*)d_in[0];
    const unsigned* adj_raw = (const unsigned*)d_in[1];
    const float* W = (const float*)d_in[2];
    const float* a = (const float*)d_in[3];
    const float* gamma = (const float*)d_in[4];
    const float* beta = (const float*)d_in[5];

    unsigned* wxb16 = (unsigned*)d_ws;                                  // 1 MB
    float* ai_s = (float*)((char*)d_ws + (1 << 20));                    // 64 KB
    unsigned* ejfj = (unsigned*)((char*)d_ws + (1 << 20) + (64 << 10)); // 64 KB
    unsigned* adjbits = (unsigned*)((char*)d_ws + (2 << 20));           // 2 MB

    k01<<<2304, 256, 0, stream>>>(adj_raw, x, W, a, adjbits, wxb16, ai_s, ejfj);
    k2_attn<<<256, 1024, 0, stream>>>(x, adjbits, wxb16, ai_s, ejfj, gamma, beta,
                                      (float*)d_out);
}